// Round 3
// baseline (293.015 us; speedup 1.0000x reference)
//
#include <hip/hip_runtime.h>
#include <cstddef>

typedef _Float16 f16;
typedef _Float16 f16x8 __attribute__((ext_vector_type(8)));
typedef _Float16 f16x4 __attribute__((ext_vector_type(4)));
typedef _Float16 f16x2 __attribute__((ext_vector_type(2)));
typedef float f32x4 __attribute__((ext_vector_type(4)));
typedef unsigned int u32;

__device__ inline float exp2_fast(float x) {
  float r;
  asm("v_exp_f32 %0, %1" : "=v"(r) : "v"(x));
  return r;
}

// Async global->LDS, 16B per lane. LDS dest must be the WAVE-UNIFORM base;
// HW writes base + lane*16. Global addr is per-lane.
__device__ inline void gl_lds16(const f16* g, f16* l) {
  __builtin_amdgcn_global_load_lds(
      (const __attribute__((address_space(1))) u32*)g,
      (__attribute__((address_space(3))) u32*)l, 16, 0, 0);
}

// ---------------------------------------------------------------------------
// Streaming convert f32 -> f16 (n multiple of 1024).
// ---------------------------------------------------------------------------
__global__ __launch_bounds__(256) void cvt_f32_f16(
    const float* __restrict__ in, f16* __restrict__ out, int n) {
  int i = (blockIdx.x * 256 + threadIdx.x) * 4;
  if (i < n) {
    float4 v = *(const float4*)&in[i];
    f16x4 h;
    h[0] = (f16)v.x; h[1] = (f16)v.y; h[2] = (f16)v.z; h[3] = (f16)v.w;
    *(f16x4*)&out[i] = h;
  }
}

// ---------------------------------------------------------------------------
// Transpose + convert: in f32 [K][N] row-major -> out f16 [N][K] row-major.
// ---------------------------------------------------------------------------
__global__ __launch_bounds__(256) void transpose_f32_to_f16(
    const float* __restrict__ in, f16* __restrict__ out, int K, int N) {
  __shared__ float t[32][33];
  int tx = threadIdx.x % 32, ty = threadIdx.x / 32;
  int n0 = blockIdx.x * 32, k0 = blockIdx.y * 32;
#pragma unroll
  for (int i = 0; i < 32; i += 8)
    t[ty + i][tx] = in[(size_t)(k0 + ty + i) * N + n0 + tx];
  __syncthreads();
#pragma unroll
  for (int i = 0; i < 32; i += 8)
    out[(size_t)(n0 + ty + i) * K + k0 + tx] = (f16)t[tx][ty + i];
}

// ---------------------------------------------------------------------------
// GEMM (m97 pattern): C[M][N] = scale * (A[M][K] @ W[K][N]), Bt = W^T f16
// [N][K]. A f16. 128x128 tile, BK=64, 256 thr = 4 waves, 4x4 16x16x32 MFMA
// per wave. Staging via global_load_lds width-16 into LINEAR (unpadded) LDS
// tiles — DMA dictates layout: block-f16-idx = i*2048 + tid*8.
// ---------------------------------------------------------------------------
template <typename CT>
__global__ __launch_bounds__(256) void gemm_lds(
    const f16* __restrict__ A, const f16* __restrict__ Bt, CT* __restrict__ C,
    int M, int N, int K, float scale) {
  constexpr int BM = 128, BN = 128, BK = 64;
  __shared__ f16 As[BM * BK];
  __shared__ f16 Bs[BN * BK];

  const int nb = N / BN;
  const int m0 = (blockIdx.x / nb) * BM;
  const int n0 = (blockIdx.x % nb) * BN;
  const int tid = threadIdx.x;
  const int w = tid >> 6, lane = tid & 63;
  const int l16 = lane & 15, quad = lane >> 4;
  const int wrow = (w >> 1) * 64, wcol = (w & 1) * 64;

  // staging map: issue i covers rows sr+i*32; lane slot = (sr+i*32)*64 + sc
  const int sr = tid >> 3, sc = (tid & 7) << 3;

  f32x4 acc[4][4] = {};

  for (int k0 = 0; k0 < K; k0 += BK) {
#pragma unroll
    for (int i = 0; i < 4; i++)
      gl_lds16(&A[(size_t)(m0 + sr + i * 32) * K + k0 + sc],
               &As[i * 2048 + w * 512]);
#pragma unroll
    for (int i = 0; i < 4; i++)
      gl_lds16(&Bt[(size_t)(n0 + sr + i * 32) * K + k0 + sc],
               &Bs[i * 2048 + w * 512]);
    __syncthreads();  // drains vmcnt -> tiles resident

    f16x8 af[4][2], bf[4][2];
#pragma unroll
    for (int mt = 0; mt < 4; mt++)
#pragma unroll
      for (int s = 0; s < 2; s++)
        af[mt][s] = *(const f16x8*)&As[(wrow + mt * 16 + l16) * 64 + s * 32 + quad * 8];
#pragma unroll
    for (int nt = 0; nt < 4; nt++)
#pragma unroll
      for (int s = 0; s < 2; s++)
        bf[nt][s] = *(const f16x8*)&Bs[(wcol + nt * 16 + l16) * 64 + s * 32 + quad * 8];

#pragma unroll
    for (int mt = 0; mt < 4; mt++)
#pragma unroll
      for (int nt = 0; nt < 4; nt++) {
        acc[mt][nt] = __builtin_amdgcn_mfma_f32_16x16x32_f16(af[mt][0], bf[nt][0], acc[mt][nt], 0, 0, 0);
        acc[mt][nt] = __builtin_amdgcn_mfma_f32_16x16x32_f16(af[mt][1], bf[nt][1], acc[mt][nt], 0, 0, 0);
      }
    __syncthreads();
  }

#pragma unroll
  for (int mt = 0; mt < 4; mt++)
#pragma unroll
    for (int nt = 0; nt < 4; nt++)
#pragma unroll
      for (int r = 0; r < 4; r++) {
        int row = m0 + wrow + mt * 16 + quad * 4 + r;
        int col = n0 + wcol + nt * 16 + l16;
        C[(size_t)row * N + col] = (CT)(acc[mt][nt][r] * scale);
      }
}

// ---------------------------------------------------------------------------
// Flash attention. Qh [4096][1024] f16 PRE-SCALED by 8*log2(e) (log2-domain
// logits come straight out of the MFMA). KV [4096][2048] f16. Yh f16.
// Block = (q-tile 64, head, batch); 4 waves x 16 q-rows; KV tile 64.
// Vt XOR-swizzled: elem (d,kv) at d*LD + ((((kv>>3)^((d>>3)&7))<<3)|(kv&7)).
// ---------------------------------------------------------------------------
__global__ __launch_bounds__(256) void attn_kernel(
    const f16* __restrict__ Qh, const f16* __restrict__ KVh, f16* __restrict__ Yh) {
  constexpr int LD = 72;
  __shared__ f16 Ks[64 * LD];  // [kv][d]
  __shared__ f16 Vt[64 * LD];  // swizzled [d][kv]
  __shared__ f16 Ps[64 * LD];  // [q][kv]

  const int qt = blockIdx.x, h = blockIdx.y, b = blockIdx.z;
  const int tid = threadIdx.x;
  const int w = tid / 64, lane = tid % 64;
  const int l16 = lane % 16, quad = lane / 16;

  const size_t qrow0 = (size_t)b * 2048 + qt * 64;
  const size_t kvrow0 = (size_t)b * 2048;

  f16x8 qf[2];
#pragma unroll
  for (int s = 0; s < 2; s++)
    qf[s] = *(const f16x8*)&Qh[(qrow0 + w * 16 + l16) * 1024 + h * 64 + s * 32 + quad * 8];

  float m_run[4], l_run[4];
  f32x4 o_acc[4] = {};
#pragma unroll
  for (int r = 0; r < 4; r++) { m_run[r] = -1e30f; l_run[r] = 0.0f; }

  const int vkv0 = (tid >> 3) * 2;
  const int vd0 = (tid & 7) * 8;
  const int vcol = ((((vkv0 >> 3) ^ (tid & 7)) << 3) | (vkv0 & 7));

  for (int t = 0; t < 2048 / 64; t++) {
#pragma unroll
    for (int i = 0; i < 2; i++) {
      int r = tid / 8 + i * 32;
      int c = (tid % 8) * 8;
      *(f16x8*)&Ks[r * LD + c] =
          *(const f16x8*)&KVh[(kvrow0 + t * 64 + r) * 2048 + h * 64 + c];
    }
    {
      const f16* vsrc = &KVh[(kvrow0 + t * 64 + vkv0) * 2048 + 1024 + h * 64 + vd0];
      f16x8 va = *(const f16x8*)vsrc;
      f16x8 vb = *(const f16x8*)(vsrc + 2048);
#pragma unroll
      for (int j = 0; j < 8; j++) {
        f16x2 p; p[0] = va[j]; p[1] = vb[j];
        *(f16x2*)&Vt[(vd0 + j) * LD + vcol] = p;
      }
    }
    __syncthreads();

    // ---- S = Q @ K^T (Q pre-scaled; logits already in log2 domain) ----
    f32x4 sacc[4];
#pragma unroll
    for (int nt = 0; nt < 4; nt++) {
      f16x8 kf0 = *(const f16x8*)&Ks[(nt * 16 + l16) * LD + quad * 8];
      f16x8 kf1 = *(const f16x8*)&Ks[(nt * 16 + l16) * LD + 32 + quad * 8];
      f32x4 z = {0.0f, 0.0f, 0.0f, 0.0f};
      z = __builtin_amdgcn_mfma_f32_16x16x32_f16(qf[0], kf0, z, 0, 0, 0);
      z = __builtin_amdgcn_mfma_f32_16x16x32_f16(qf[1], kf1, z, 0, 0, 0);
      sacc[nt] = z;
    }

    // ---- online softmax ----
    float mnew[4], alpha[4];
#pragma unroll
    for (int r = 0; r < 4; r++) {
      float mx = fmaxf(fmaxf(sacc[0][r], sacc[1][r]), fmaxf(sacc[2][r], sacc[3][r]));
#pragma unroll
      for (int off = 1; off < 16; off <<= 1) mx = fmaxf(mx, __shfl_xor(mx, off, 64));
      mnew[r] = fmaxf(m_run[r], mx);
      alpha[r] = exp2_fast(m_run[r] - mnew[r]);
      m_run[r] = mnew[r];
    }
#pragma unroll
    for (int nt = 0; nt < 4; nt++)
#pragma unroll
      for (int r = 0; r < 4; r++) {
        float p = exp2_fast(sacc[nt][r] - mnew[r]);
        sacc[nt][r] = p;
        Ps[(w * 16 + quad * 4 + r) * LD + nt * 16 + l16] = (f16)p;
      }
#pragma unroll
    for (int r = 0; r < 4; r++) {
      float s = sacc[0][r] + sacc[1][r] + sacc[2][r] + sacc[3][r];
#pragma unroll
      for (int off = 1; off < 16; off <<= 1) s += __shfl_xor(s, off, 64);
      l_run[r] = l_run[r] * alpha[r] + s;
#pragma unroll
      for (int nt = 0; nt < 4; nt++) o_acc[nt][r] *= alpha[r];
    }
    // no barrier: Ps rows [w*16, w*16+15] written+read only by wave w.

    // ---- O += P @ V ----
    f16x8 pf0 = *(const f16x8*)&Ps[(w * 16 + l16) * LD + quad * 8];
    f16x8 pf1 = *(const f16x8*)&Ps[(w * 16 + l16) * LD + 32 + quad * 8];
#pragma unroll
    for (int nt = 0; nt < 4; nt++) {
      const int drow = nt * 16 + l16;
      const int xv = (drow >> 3) & 7;
      f16x8 vf0 = *(const f16x8*)&Vt[drow * LD + ((quad ^ xv) << 3)];
      f16x8 vf1 = *(const f16x8*)&Vt[drow * LD + (((quad + 4) ^ xv) << 3)];
      o_acc[nt] = __builtin_amdgcn_mfma_f32_16x16x32_f16(pf0, vf0, o_acc[nt], 0, 0, 0);
      o_acc[nt] = __builtin_amdgcn_mfma_f32_16x16x32_f16(pf1, vf1, o_acc[nt], 0, 0, 0);
    }
    __syncthreads();
  }

#pragma unroll
  for (int r = 0; r < 4; r++) {
    float inv = 1.0f / l_run[r];
    size_t row = qrow0 + w * 16 + quad * 4 + r;
#pragma unroll
    for (int nt = 0; nt < 4; nt++)
      Yh[row * 1024 + h * 64 + nt * 16 + l16] = (f16)(o_acc[nt][r] * inv);
  }
}

// ---------------------------------------------------------------------------
extern "C" void kernel_launch(void* const* d_in, const int* in_sizes, int n_in,
                              void* d_out, int out_size, void* d_ws, size_t ws_size,
                              hipStream_t stream) {
  const float* x_q  = (const float*)d_in[0];
  const float* x_kv = (const float*)d_in[1];
  const float* W_q  = (const float*)d_in[2];
  const float* W_kv = (const float*)d_in[3];
  const float* W_p  = (const float*)d_in[4];
  float* out = (float*)d_out;

  // workspace (f16 elements), 48 MB total. Xq_h aliases Yh (Xq_h dead after
  // the Q-GEMM; Yh first written by attn).
  f16* Wq_t  = (f16*)d_ws;                       // [1024][1024]
  f16* Wkv_t = Wq_t  + (size_t)1024 * 1024;      // [2048][1024]
  f16* Wp_t  = Wkv_t + (size_t)2048 * 1024;      // [1024][1024]
  f16* Qh    = Wp_t  + (size_t)1024 * 1024;      // [4096][1024]
  f16* KVh   = Qh    + (size_t)4096 * 1024;      // [4096][2048]
  f16* Yh    = KVh   + (size_t)4096 * 2048;      // [4096][1024]
  f16* Xq_h  = Yh;                               // alias
  f16* Xkv_h = Yh    + (size_t)4096 * 1024;      // [4096][1024]

  const int NX = 4096 * 1024;
  cvt_f32_f16<<<NX / 1024, 256, 0, stream>>>(x_q,  Xq_h,  NX);
  cvt_f32_f16<<<NX / 1024, 256, 0, stream>>>(x_kv, Xkv_h, NX);

  transpose_f32_to_f16<<<dim3(32, 32), 256, 0, stream>>>(W_q,  Wq_t,  1024, 1024);
  transpose_f32_to_f16<<<dim3(64, 32), 256, 0, stream>>>(W_kv, Wkv_t, 1024, 2048);
  transpose_f32_to_f16<<<dim3(32, 32), 256, 0, stream>>>(W_p,  Wp_t,  1024, 1024);

  const float SC = 11.5415603f;  // 8 * log2(e)
  gemm_lds<f16><<<256, 256, 0, stream>>>(Xq_h,  Wq_t,  Qh,  4096, 1024, 1024, SC);
  gemm_lds<f16><<<512, 256, 0, stream>>>(Xkv_h, Wkv_t, KVh, 4096, 2048, 1024, 1.0f);

  attn_kernel<<<dim3(32, 16, 2), 256, 0, stream>>>(Qh, KVh, Yh);

  gemm_lds<float><<<256, 256, 0, stream>>>(Yh, Wp_t, out, 4096, 1024, 1024, 1.0f);
}

// Round 4
// 281.280 us; speedup vs baseline: 1.0417x; 1.0417x over previous
//
#include <hip/hip_runtime.h>
#include <cstddef>

typedef _Float16 f16;
typedef _Float16 f16x8 __attribute__((ext_vector_type(8)));
typedef _Float16 f16x4 __attribute__((ext_vector_type(4)));
typedef _Float16 f16x2 __attribute__((ext_vector_type(2)));
typedef float f32x4 __attribute__((ext_vector_type(4)));
typedef unsigned int u32;

__device__ inline float exp2_fast(float x) {
  float r;
  asm("v_exp_f32 %0, %1" : "=v"(r) : "v"(x));
  return r;
}

// Async global->LDS, 16B per lane. LDS dest is the wave-uniform base;
// HW writes base + lane*16.
__device__ inline void gl_lds16(const f16* g, f16* l) {
  __builtin_amdgcn_global_load_lds(
      (const __attribute__((address_space(1))) u32*)g,
      (__attribute__((address_space(3))) u32*)l, 16, 0, 0);
}

// ---------------------------------------------------------------------------
// Fused convert f32 -> f16 for both activation tensors (4M elems each).
// ---------------------------------------------------------------------------
__global__ __launch_bounds__(256) void cvt2_f32_f16(
    const float* __restrict__ a, const float* __restrict__ b,
    f16* __restrict__ oa, f16* __restrict__ ob) {
  int bid = blockIdx.x;
  const float* in;
  f16* out;
  if (bid < 4096) { in = a; out = oa; } else { in = b; out = ob; bid -= 4096; }
  int i = (bid * 256 + threadIdx.x) * 4;
  float4 v = *(const float4*)&in[i];
  f16x4 h;
  h[0] = (f16)v.x; h[1] = (f16)v.y; h[2] = (f16)v.z; h[3] = (f16)v.w;
  *(f16x4*)&out[i] = h;
}

// ---------------------------------------------------------------------------
// Fused transpose+convert of all three weight matrices: f32 [1024][N] ->
// f16 [N][1024]. z=0: W_q, z=1/2: W_kv halves, z=3: W_proj.
// ---------------------------------------------------------------------------
__global__ __launch_bounds__(256) void transpose3(
    const float* __restrict__ Wq, const float* __restrict__ Wkv,
    const float* __restrict__ Wp, f16* __restrict__ Wqt,
    f16* __restrict__ Wkvt, f16* __restrict__ Wpt) {
  __shared__ float t[32][33];
  int z = blockIdx.z;
  const float* in;
  f16* out;
  int N = 1024, extra = 0;
  if (z == 0) { in = Wq; out = Wqt; }
  else if (z == 3) { in = Wp; out = Wpt; }
  else { in = Wkv; out = Wkvt; N = 2048; extra = (z - 1) * 1024; }
  int tx = threadIdx.x % 32, ty = threadIdx.x / 32;
  int n0 = blockIdx.x * 32 + extra, k0 = blockIdx.y * 32;
#pragma unroll
  for (int i = 0; i < 32; i += 8)
    t[ty + i][tx] = in[(size_t)(k0 + ty + i) * N + n0 + tx];
  __syncthreads();
#pragma unroll
  for (int i = 0; i < 32; i += 8)
    out[(size_t)(n0 + ty + i) * 1024 + k0 + tx] = (f16)t[tx][ty + i];
}

// ---------------------------------------------------------------------------
// GEMM body (m97 pattern): C = scale*(A @ W), Bt = W^T f16 [N][K], A f16.
// BM=128 fixed, BN templated (128 or 64). BK=64, 256 thr = 4 waves (2x2),
// wave tile 64 x BN/2. global_load_lds width-16 into linear LDS tiles.
// ---------------------------------------------------------------------------
template <int BN, typename CT>
__device__ __forceinline__ void gemm_body(
    const f16* __restrict__ A, const f16* __restrict__ Bt, CT* __restrict__ C,
    int bid, int M, int N, int K, float scale, f16* As, f16* Bs) {
  constexpr int NT = BN / 32;   // nt tiles per wave
  constexpr int BI = BN / 32;   // B staging issues
  const int nb = N / BN;
  const int m0 = (bid / nb) * 128;
  const int n0 = (bid % nb) * BN;
  const int tid = threadIdx.x;
  const int w = tid >> 6, lane = tid & 63;
  const int l16 = lane & 15, quad = lane >> 4;
  const int wrow = (w >> 1) * 64, wcol = (w & 1) * (BN / 2);
  const int sr = tid >> 3, sc = (tid & 7) << 3;

  f32x4 acc[4][NT] = {};

  for (int k0 = 0; k0 < K; k0 += 64) {
#pragma unroll
    for (int i = 0; i < 4; i++)
      gl_lds16(&A[(size_t)(m0 + sr + i * 32) * K + k0 + sc],
               &As[i * 2048 + w * 512]);
#pragma unroll
    for (int i = 0; i < BI; i++)
      gl_lds16(&Bt[(size_t)(n0 + sr + i * 32) * K + k0 + sc],
               &Bs[i * 2048 + w * 512]);
    __syncthreads();

    f16x8 af[4][2], bf[NT][2];
#pragma unroll
    for (int mt = 0; mt < 4; mt++)
#pragma unroll
      for (int s = 0; s < 2; s++)
        af[mt][s] = *(const f16x8*)&As[(wrow + mt * 16 + l16) * 64 + s * 32 + quad * 8];
#pragma unroll
    for (int nt = 0; nt < NT; nt++)
#pragma unroll
      for (int s = 0; s < 2; s++)
        bf[nt][s] = *(const f16x8*)&Bs[(wcol + nt * 16 + l16) * 64 + s * 32 + quad * 8];

#pragma unroll
    for (int mt = 0; mt < 4; mt++)
#pragma unroll
      for (int nt = 0; nt < NT; nt++) {
        acc[mt][nt] = __builtin_amdgcn_mfma_f32_16x16x32_f16(af[mt][0], bf[nt][0], acc[mt][nt], 0, 0, 0);
        acc[mt][nt] = __builtin_amdgcn_mfma_f32_16x16x32_f16(af[mt][1], bf[nt][1], acc[mt][nt], 0, 0, 0);
      }
    __syncthreads();
  }

#pragma unroll
  for (int mt = 0; mt < 4; mt++)
#pragma unroll
    for (int nt = 0; nt < NT; nt++)
#pragma unroll
      for (int r = 0; r < 4; r++) {
        int row = m0 + wrow + mt * 16 + quad * 4 + r;
        int col = n0 + wcol + nt * 16 + l16;
        C[(size_t)row * N + col] = (CT)(acc[mt][nt][r] * scale);
      }
}

// Fused Q + KV projection GEMMs: blocks [0,256) -> Q (N=1024, pre-scaled for
// log2-domain softmax), blocks [256,768) -> KV (N=2048). 768 blocks = 3/CU.
__global__ __launch_bounds__(256) void qkv_gemm(
    const f16* __restrict__ Xq, const f16* __restrict__ Wqt, f16* __restrict__ Qh,
    const f16* __restrict__ Xkv, const f16* __restrict__ Wkvt, f16* __restrict__ KVh,
    float sc_q) {
  __shared__ f16 As[128 * 64];
  __shared__ f16 Bs[128 * 64];
  if (blockIdx.x < 256)
    gemm_body<128, f16>(Xq, Wqt, Qh, blockIdx.x, 4096, 1024, 1024, sc_q, As, Bs);
  else
    gemm_body<128, f16>(Xkv, Wkvt, KVh, blockIdx.x - 256, 4096, 2048, 1024, 1.0f, As, Bs);
}

// Standalone GEMM (proj uses BN=64 -> 512 blocks = 2/CU).
template <int BN, typename CT>
__global__ __launch_bounds__(256) void gemm_lds(
    const f16* __restrict__ A, const f16* __restrict__ Bt, CT* __restrict__ C,
    int M, int N, int K, float scale) {
  __shared__ f16 As[128 * 64];
  __shared__ f16 Bs[BN * 64];
  gemm_body<BN, CT>(A, Bt, C, blockIdx.x, M, N, K, scale, As, Bs);
}

// ---------------------------------------------------------------------------
// Flash attention (unchanged from round 3 — control). Qh pre-scaled by
// 8*log2(e). Vt XOR-swizzled; log2-domain softmax.
// ---------------------------------------------------------------------------
__global__ __launch_bounds__(256) void attn_kernel(
    const f16* __restrict__ Qh, const f16* __restrict__ KVh, f16* __restrict__ Yh) {
  constexpr int LD = 72;
  __shared__ f16 Ks[64 * LD];
  __shared__ f16 Vt[64 * LD];
  __shared__ f16 Ps[64 * LD];

  const int qt = blockIdx.x, h = blockIdx.y, b = blockIdx.z;
  const int tid = threadIdx.x;
  const int w = tid / 64, lane = tid % 64;
  const int l16 = lane % 16, quad = lane / 16;

  const size_t qrow0 = (size_t)b * 2048 + qt * 64;
  const size_t kvrow0 = (size_t)b * 2048;

  f16x8 qf[2];
#pragma unroll
  for (int s = 0; s < 2; s++)
    qf[s] = *(const f16x8*)&Qh[(qrow0 + w * 16 + l16) * 1024 + h * 64 + s * 32 + quad * 8];

  float m_run[4], l_run[4];
  f32x4 o_acc[4] = {};
#pragma unroll
  for (int r = 0; r < 4; r++) { m_run[r] = -1e30f; l_run[r] = 0.0f; }

  const int vkv0 = (tid >> 3) * 2;
  const int vd0 = (tid & 7) * 8;
  const int vcol = ((((vkv0 >> 3) ^ (tid & 7)) << 3) | (vkv0 & 7));

  for (int t = 0; t < 2048 / 64; t++) {
#pragma unroll
    for (int i = 0; i < 2; i++) {
      int r = tid / 8 + i * 32;
      int c = (tid % 8) * 8;
      *(f16x8*)&Ks[r * LD + c] =
          *(const f16x8*)&KVh[(kvrow0 + t * 64 + r) * 2048 + h * 64 + c];
    }
    {
      const f16* vsrc = &KVh[(kvrow0 + t * 64 + vkv0) * 2048 + 1024 + h * 64 + vd0];
      f16x8 va = *(const f16x8*)vsrc;
      f16x8 vb = *(const f16x8*)(vsrc + 2048);
#pragma unroll
      for (int j = 0; j < 8; j++) {
        f16x2 p; p[0] = va[j]; p[1] = vb[j];
        *(f16x2*)&Vt[(vd0 + j) * LD + vcol] = p;
      }
    }
    __syncthreads();

    f32x4 sacc[4];
#pragma unroll
    for (int nt = 0; nt < 4; nt++) {
      f16x8 kf0 = *(const f16x8*)&Ks[(nt * 16 + l16) * LD + quad * 8];
      f16x8 kf1 = *(const f16x8*)&Ks[(nt * 16 + l16) * LD + 32 + quad * 8];
      f32x4 z = {0.0f, 0.0f, 0.0f, 0.0f};
      z = __builtin_amdgcn_mfma_f32_16x16x32_f16(qf[0], kf0, z, 0, 0, 0);
      z = __builtin_amdgcn_mfma_f32_16x16x32_f16(qf[1], kf1, z, 0, 0, 0);
      sacc[nt] = z;
    }

    float mnew[4], alpha[4];
#pragma unroll
    for (int r = 0; r < 4; r++) {
      float mx = fmaxf(fmaxf(sacc[0][r], sacc[1][r]), fmaxf(sacc[2][r], sacc[3][r]));
#pragma unroll
      for (int off = 1; off < 16; off <<= 1) mx = fmaxf(mx, __shfl_xor(mx, off, 64));
      mnew[r] = fmaxf(m_run[r], mx);
      alpha[r] = exp2_fast(m_run[r] - mnew[r]);
      m_run[r] = mnew[r];
    }
#pragma unroll
    for (int nt = 0; nt < 4; nt++)
#pragma unroll
      for (int r = 0; r < 4; r++) {
        float p = exp2_fast(sacc[nt][r] - mnew[r]);
        sacc[nt][r] = p;
        Ps[(w * 16 + quad * 4 + r) * LD + nt * 16 + l16] = (f16)p;
      }
#pragma unroll
    for (int r = 0; r < 4; r++) {
      float s = sacc[0][r] + sacc[1][r] + sacc[2][r] + sacc[3][r];
#pragma unroll
      for (int off = 1; off < 16; off <<= 1) s += __shfl_xor(s, off, 64);
      l_run[r] = l_run[r] * alpha[r] + s;
#pragma unroll
      for (int nt = 0; nt < 4; nt++) o_acc[nt][r] *= alpha[r];
    }
    // no barrier: Ps rows [w*16, w*16+15] written+read only by wave w.

    f16x8 pf0 = *(const f16x8*)&Ps[(w * 16 + l16) * LD + quad * 8];
    f16x8 pf1 = *(const f16x8*)&Ps[(w * 16 + l16) * LD + 32 + quad * 8];
#pragma unroll
    for (int nt = 0; nt < 4; nt++) {
      const int drow = nt * 16 + l16;
      const int xv = (drow >> 3) & 7;
      f16x8 vf0 = *(const f16x8*)&Vt[drow * LD + ((quad ^ xv) << 3)];
      f16x8 vf1 = *(const f16x8*)&Vt[drow * LD + (((quad + 4) ^ xv) << 3)];
      o_acc[nt] = __builtin_amdgcn_mfma_f32_16x16x32_f16(pf0, vf0, o_acc[nt], 0, 0, 0);
      o_acc[nt] = __builtin_amdgcn_mfma_f32_16x16x32_f16(pf1, vf1, o_acc[nt], 0, 0, 0);
    }
    __syncthreads();
  }

#pragma unroll
  for (int r = 0; r < 4; r++) {
    float inv = 1.0f / l_run[r];
    size_t row = qrow0 + w * 16 + quad * 4 + r;
#pragma unroll
    for (int nt = 0; nt < 4; nt++)
      Yh[row * 1024 + h * 64 + nt * 16 + l16] = (f16)(o_acc[nt][r] * inv);
  }
}

// ---------------------------------------------------------------------------
extern "C" void kernel_launch(void* const* d_in, const int* in_sizes, int n_in,
                              void* d_out, int out_size, void* d_ws, size_t ws_size,
                              hipStream_t stream) {
  const float* x_q  = (const float*)d_in[0];
  const float* x_kv = (const float*)d_in[1];
  const float* W_q  = (const float*)d_in[2];
  const float* W_kv = (const float*)d_in[3];
  const float* W_p  = (const float*)d_in[4];
  float* out = (float*)d_out;

  f16* Wq_t  = (f16*)d_ws;                       // [1024][1024]
  f16* Wkv_t = Wq_t  + (size_t)1024 * 1024;      // [2048][1024]
  f16* Wp_t  = Wkv_t + (size_t)2048 * 1024;      // [1024][1024]
  f16* Qh    = Wp_t  + (size_t)1024 * 1024;      // [4096][1024]
  f16* KVh   = Qh    + (size_t)4096 * 1024;      // [4096][2048]
  f16* Yh    = KVh   + (size_t)4096 * 2048;      // [4096][1024]
  f16* Xq_h  = Yh;                               // alias (dead after qkv_gemm)
  f16* Xkv_h = Yh    + (size_t)4096 * 1024;      // [4096][1024]

  cvt2_f32_f16<<<8192, 256, 0, stream>>>(x_q, x_kv, Xq_h, Xkv_h);
  transpose3<<<dim3(32, 32, 4), 256, 0, stream>>>(W_q, W_kv, W_p, Wq_t, Wkv_t, Wp_t);

  const float SC = 11.5415603f;  // 8 * log2(e)
  qkv_gemm<<<768, 256, 0, stream>>>(Xq_h, Wq_t, Qh, Xkv_h, Wkv_t, KVh, SC);

  attn_kernel<<<dim3(32, 16, 2), 256, 0, stream>>>(Qh, KVh, Yh);

  gemm_lds<64, float><<<512, 256, 0, stream>>>(Yh, Wp_t, out, 4096, 1024, 1024, 1.0f);
}

// Round 5
// 277.180 us; speedup vs baseline: 1.0571x; 1.0148x over previous
//
#include <hip/hip_runtime.h>
#include <cstddef>

typedef _Float16 f16;
typedef _Float16 f16x8 __attribute__((ext_vector_type(8)));
typedef _Float16 f16x4 __attribute__((ext_vector_type(4)));
typedef _Float16 f16x2 __attribute__((ext_vector_type(2)));
typedef float f32x4 __attribute__((ext_vector_type(4)));
typedef unsigned int u32;

__device__ inline float exp2_fast(float x) {
  float r;
  asm("v_exp_f32 %0, %1" : "=v"(r) : "v"(x));
  return r;
}

// Async global->LDS, 16B per lane. LDS dest is the wave-uniform base;
// HW writes base + lane*16.
__device__ inline void gl_lds16(const f16* g, f16* l) {
  __builtin_amdgcn_global_load_lds(
      (const __attribute__((address_space(1))) u32*)g,
      (__attribute__((address_space(3))) u32*)l, 16, 0, 0);
}

// ---------------------------------------------------------------------------
// Fused convert f32 -> f16 for both activation tensors (4M elems each).
// ---------------------------------------------------------------------------
__global__ __launch_bounds__(256) void cvt2_f32_f16(
    const float* __restrict__ a, const float* __restrict__ b,
    f16* __restrict__ oa, f16* __restrict__ ob) {
  int bid = blockIdx.x;
  const float* in;
  f16* out;
  if (bid < 4096) { in = a; out = oa; } else { in = b; out = ob; bid -= 4096; }
  int i = (bid * 256 + threadIdx.x) * 4;
  float4 v = *(const float4*)&in[i];
  f16x4 h;
  h[0] = (f16)v.x; h[1] = (f16)v.y; h[2] = (f16)v.z; h[3] = (f16)v.w;
  *(f16x4*)&out[i] = h;
}

// ---------------------------------------------------------------------------
// Fused transpose+convert of all three weight matrices: f32 [1024][N] ->
// f16 [N][1024]. z=0: W_q, z=1/2: W_kv halves, z=3: W_proj.
// ---------------------------------------------------------------------------
__global__ __launch_bounds__(256) void transpose3(
    const float* __restrict__ Wq, const float* __restrict__ Wkv,
    const float* __restrict__ Wp, f16* __restrict__ Wqt,
    f16* __restrict__ Wkvt, f16* __restrict__ Wpt) {
  __shared__ float t[32][33];
  int z = blockIdx.z;
  const float* in;
  f16* out;
  int N = 1024, extra = 0;
  if (z == 0) { in = Wq; out = Wqt; }
  else if (z == 3) { in = Wp; out = Wpt; }
  else { in = Wkv; out = Wkvt; N = 2048; extra = (z - 1) * 1024; }
  int tx = threadIdx.x % 32, ty = threadIdx.x / 32;
  int n0 = blockIdx.x * 32 + extra, k0 = blockIdx.y * 32;
#pragma unroll
  for (int i = 0; i < 32; i += 8)
    t[ty + i][tx] = in[(size_t)(k0 + ty + i) * N + n0 + tx];
  __syncthreads();
#pragma unroll
  for (int i = 0; i < 32; i += 8)
    out[(size_t)(n0 + ty + i) * 1024 + k0 + tx] = (f16)t[tx][ty + i];
}

// ---------------------------------------------------------------------------
// GEMM body (m97 pattern): C = scale*(A @ W), Bt = W^T f16 [N][K], A f16.
// BM=128 fixed, BN templated. BK=64, 256 thr = 4 waves (2x2).
// ---------------------------------------------------------------------------
template <int BN, typename CT>
__device__ __forceinline__ void gemm_body(
    const f16* __restrict__ A, const f16* __restrict__ Bt, CT* __restrict__ C,
    int bid, int M, int N, int K, float scale, f16* As, f16* Bs) {
  constexpr int NT = BN / 32;
  constexpr int BI = BN / 32;
  const int nb = N / BN;
  const int m0 = (bid / nb) * 128;
  const int n0 = (bid % nb) * BN;
  const int tid = threadIdx.x;
  const int w = tid >> 6, lane = tid & 63;
  const int l16 = lane & 15, quad = lane >> 4;
  const int wrow = (w >> 1) * 64, wcol = (w & 1) * (BN / 2);
  const int sr = tid >> 3, sc = (tid & 7) << 3;

  f32x4 acc[4][NT] = {};

  for (int k0 = 0; k0 < K; k0 += 64) {
#pragma unroll
    for (int i = 0; i < 4; i++)
      gl_lds16(&A[(size_t)(m0 + sr + i * 32) * K + k0 + sc],
               &As[i * 2048 + w * 512]);
#pragma unroll
    for (int i = 0; i < BI; i++)
      gl_lds16(&Bt[(size_t)(n0 + sr + i * 32) * K + k0 + sc],
               &Bs[i * 2048 + w * 512]);
    __syncthreads();

    f16x8 af[4][2], bf[NT][2];
#pragma unroll
    for (int mt = 0; mt < 4; mt++)
#pragma unroll
      for (int s = 0; s < 2; s++)
        af[mt][s] = *(const f16x8*)&As[(wrow + mt * 16 + l16) * 64 + s * 32 + quad * 8];
#pragma unroll
    for (int nt = 0; nt < NT; nt++)
#pragma unroll
      for (int s = 0; s < 2; s++)
        bf[nt][s] = *(const f16x8*)&Bs[(wcol + nt * 16 + l16) * 64 + s * 32 + quad * 8];

#pragma unroll
    for (int mt = 0; mt < 4; mt++)
#pragma unroll
      for (int nt = 0; nt < NT; nt++) {
        acc[mt][nt] = __builtin_amdgcn_mfma_f32_16x16x32_f16(af[mt][0], bf[nt][0], acc[mt][nt], 0, 0, 0);
        acc[mt][nt] = __builtin_amdgcn_mfma_f32_16x16x32_f16(af[mt][1], bf[nt][1], acc[mt][nt], 0, 0, 0);
      }
    __syncthreads();
  }

#pragma unroll
  for (int mt = 0; mt < 4; mt++)
#pragma unroll
    for (int nt = 0; nt < NT; nt++)
#pragma unroll
      for (int r = 0; r < 4; r++) {
        int row = m0 + wrow + mt * 16 + quad * 4 + r;
        int col = n0 + wcol + nt * 16 + l16;
        C[(size_t)row * N + col] = (CT)(acc[mt][nt][r] * scale);
      }
}

// Fused Q + KV projection GEMMs: blocks [0,256) -> Q (pre-scaled for
// log2-domain softmax), blocks [256,768) -> KV. 768 blocks = 3/CU.
__global__ __launch_bounds__(256) void qkv_gemm(
    const f16* __restrict__ Xq, const f16* __restrict__ Wqt, f16* __restrict__ Qh,
    const f16* __restrict__ Xkv, const f16* __restrict__ Wkvt, f16* __restrict__ KVh,
    float sc_q) {
  __shared__ f16 As[128 * 64];
  __shared__ f16 Bs[128 * 64];
  if (blockIdx.x < 256)
    gemm_body<128, f16>(Xq, Wqt, Qh, blockIdx.x, 4096, 1024, 1024, sc_q, As, Bs);
  else
    gemm_body<128, f16>(Xkv, Wkvt, KVh, blockIdx.x - 256, 4096, 2048, 1024, 1.0f, As, Bs);
}

template <int BN, typename CT>
__global__ __launch_bounds__(256) void gemm_lds(
    const f16* __restrict__ A, const f16* __restrict__ Bt, CT* __restrict__ C,
    int M, int N, int K, float scale) {
  __shared__ f16 As[128 * 64];
  __shared__ f16 Bs[BN * 64];
  gemm_body<BN, CT>(A, Bt, C, blockIdx.x, M, N, K, scale, As, Bs);
}

// ---------------------------------------------------------------------------
// Flash attention, round 5: register-prefetch pipeline + XCD-aware swizzle.
// Qh pre-scaled by 8*log2(e); log2-domain softmax; Vt XOR-swizzled.
// Linear grid of 1024: hb = bid&31 (h=hb>>1, b=hb&1), qt = bid>>5 -> all 32
// q-tiles of one (h,b) land on one XCD (bid%8 round-robin), so the 512 KB
// KV working set stays in that XCD's L2 (4 hb-pairs x 512 KB = 2 MB < 4 MB).
// K/V tile t+1 is loaded into registers right after the barrier, hidden
// under tile t's compute; written to LDS at the top of the next iteration.
// ---------------------------------------------------------------------------
__global__ __launch_bounds__(256) void attn_kernel(
    const f16* __restrict__ Qh, const f16* __restrict__ KVh, f16* __restrict__ Yh) {
  constexpr int LD = 72;
  __shared__ f16 Ks[64 * LD];
  __shared__ f16 Vt[64 * LD];
  __shared__ f16 Ps[64 * LD];

  const int bid = blockIdx.x;
  const int hb = bid & 31;
  const int qt = bid >> 5;
  const int h = hb >> 1, b = hb & 1;
  const int tid = threadIdx.x;
  const int w = tid / 64, lane = tid % 64;
  const int l16 = lane % 16, quad = lane / 16;

  const size_t qrow0 = (size_t)b * 2048 + qt * 64;
  const size_t kvrow0 = (size_t)b * 2048;

  f16x8 qf[2];
#pragma unroll
  for (int s = 0; s < 2; s++)
    qf[s] = *(const f16x8*)&Qh[(qrow0 + w * 16 + l16) * 1024 + h * 64 + s * 32 + quad * 8];

  float m_run[4], l_run[4];
  f32x4 o_acc[4] = {};
#pragma unroll
  for (int r = 0; r < 4; r++) { m_run[r] = -1e30f; l_run[r] = 0.0f; }

  // staging maps
  const int ksr = tid >> 3;            // kv row (i=0: +0, i=1: +32)
  const int ksc = (tid & 7) << 3;      // d col
  const int vkv0 = (tid >> 3) * 2;
  const int vd0 = (tid & 7) * 8;
  const int vcol = ((((vkv0 >> 3) ^ (tid & 7)) << 3) | (vkv0 & 7));

  // prefetch tile 0 into registers
  f16x8 kr0, kr1, vr0, vr1;
  {
    const f16* kb = &KVh[(kvrow0 + ksr) * 2048 + h * 64 + ksc];
    kr0 = *(const f16x8*)kb;
    kr1 = *(const f16x8*)(kb + (size_t)32 * 2048);
    const f16* vb = &KVh[(kvrow0 + vkv0) * 2048 + 1024 + h * 64 + vd0];
    vr0 = *(const f16x8*)vb;
    vr1 = *(const f16x8*)(vb + 2048);
  }

  for (int t = 0; t < 2048 / 64; t++) {
    // ---- commit prefetched tile to LDS ----
    *(f16x8*)&Ks[ksr * LD + ksc] = kr0;
    *(f16x8*)&Ks[(ksr + 32) * LD + ksc] = kr1;
#pragma unroll
    for (int j = 0; j < 8; j++) {
      f16x2 p; p[0] = vr0[j]; p[1] = vr1[j];
      *(f16x2*)&Vt[(vd0 + j) * LD + vcol] = p;
    }
    __syncthreads();

    // ---- issue next tile's global loads (hidden under compute) ----
    if (t + 1 < 2048 / 64) {
      const f16* kb = &KVh[(kvrow0 + (t + 1) * 64 + ksr) * 2048 + h * 64 + ksc];
      kr0 = *(const f16x8*)kb;
      kr1 = *(const f16x8*)(kb + (size_t)32 * 2048);
      const f16* vb = &KVh[(kvrow0 + (t + 1) * 64 + vkv0) * 2048 + 1024 + h * 64 + vd0];
      vr0 = *(const f16x8*)vb;
      vr1 = *(const f16x8*)(vb + 2048);
    }

    // ---- S = Q @ K^T (Q pre-scaled; log2-domain logits) ----
    f32x4 sacc[4];
#pragma unroll
    for (int nt = 0; nt < 4; nt++) {
      f16x8 kf0 = *(const f16x8*)&Ks[(nt * 16 + l16) * LD + quad * 8];
      f16x8 kf1 = *(const f16x8*)&Ks[(nt * 16 + l16) * LD + 32 + quad * 8];
      f32x4 z = {0.0f, 0.0f, 0.0f, 0.0f};
      z = __builtin_amdgcn_mfma_f32_16x16x32_f16(qf[0], kf0, z, 0, 0, 0);
      z = __builtin_amdgcn_mfma_f32_16x16x32_f16(qf[1], kf1, z, 0, 0, 0);
      sacc[nt] = z;
    }

    // ---- online softmax ----
    float mnew[4], alpha[4];
#pragma unroll
    for (int r = 0; r < 4; r++) {
      float mx = fmaxf(fmaxf(sacc[0][r], sacc[1][r]), fmaxf(sacc[2][r], sacc[3][r]));
#pragma unroll
      for (int off = 1; off < 16; off <<= 1) mx = fmaxf(mx, __shfl_xor(mx, off, 64));
      mnew[r] = fmaxf(m_run[r], mx);
      alpha[r] = exp2_fast(m_run[r] - mnew[r]);
      m_run[r] = mnew[r];
    }
#pragma unroll
    for (int nt = 0; nt < 4; nt++)
#pragma unroll
      for (int r = 0; r < 4; r++) {
        float p = exp2_fast(sacc[nt][r] - mnew[r]);
        sacc[nt][r] = p;
        Ps[(w * 16 + quad * 4 + r) * LD + nt * 16 + l16] = (f16)p;
      }
#pragma unroll
    for (int r = 0; r < 4; r++) {
      float s = sacc[0][r] + sacc[1][r] + sacc[2][r] + sacc[3][r];
#pragma unroll
      for (int off = 1; off < 16; off <<= 1) s += __shfl_xor(s, off, 64);
      l_run[r] = l_run[r] * alpha[r] + s;
#pragma unroll
      for (int nt = 0; nt < 4; nt++) o_acc[nt][r] *= alpha[r];
    }
    // no barrier: Ps rows [w*16, w*16+15] written+read only by wave w.

    // ---- O += P @ V ----
    f16x8 pf0 = *(const f16x8*)&Ps[(w * 16 + l16) * LD + quad * 8];
    f16x8 pf1 = *(const f16x8*)&Ps[(w * 16 + l16) * LD + 32 + quad * 8];
#pragma unroll
    for (int nt = 0; nt < 4; nt++) {
      const int drow = nt * 16 + l16;
      const int xv = (drow >> 3) & 7;
      f16x8 vf0 = *(const f16x8*)&Vt[drow * LD + ((quad ^ xv) << 3)];
      f16x8 vf1 = *(const f16x8*)&Vt[drow * LD + (((quad + 4) ^ xv) << 3)];
      o_acc[nt] = __builtin_amdgcn_mfma_f32_16x16x32_f16(pf0, vf0, o_acc[nt], 0, 0, 0);
      o_acc[nt] = __builtin_amdgcn_mfma_f32_16x16x32_f16(pf1, vf1, o_acc[nt], 0, 0, 0);
    }
    __syncthreads();  // protect Ks/Vt before next commit
  }

#pragma unroll
  for (int r = 0; r < 4; r++) {
    float inv = 1.0f / l_run[r];
    size_t row = qrow0 + w * 16 + quad * 4 + r;
#pragma unroll
    for (int nt = 0; nt < 4; nt++)
      Yh[row * 1024 + h * 64 + nt * 16 + l16] = (f16)(o_acc[nt][r] * inv);
  }
}

// ---------------------------------------------------------------------------
extern "C" void kernel_launch(void* const* d_in, const int* in_sizes, int n_in,
                              void* d_out, int out_size, void* d_ws, size_t ws_size,
                              hipStream_t stream) {
  const float* x_q  = (const float*)d_in[0];
  const float* x_kv = (const float*)d_in[1];
  const float* W_q  = (const float*)d_in[2];
  const float* W_kv = (const float*)d_in[3];
  const float* W_p  = (const float*)d_in[4];
  float* out = (float*)d_out;

  f16* Wq_t  = (f16*)d_ws;                       // [1024][1024]
  f16* Wkv_t = Wq_t  + (size_t)1024 * 1024;      // [2048][1024]
  f16* Wp_t  = Wkv_t + (size_t)2048 * 1024;      // [1024][1024]
  f16* Qh    = Wp_t  + (size_t)1024 * 1024;      // [4096][1024]
  f16* KVh   = Qh    + (size_t)4096 * 1024;      // [4096][2048]
  f16* Yh    = KVh   + (size_t)4096 * 2048;      // [4096][1024]
  f16* Xq_h  = Yh;                               // alias (dead after qkv_gemm)
  f16* Xkv_h = Yh    + (size_t)4096 * 1024;      // [4096][1024]

  cvt2_f32_f16<<<8192, 256, 0, stream>>>(x_q, x_kv, Xq_h, Xkv_h);
  transpose3<<<dim3(32, 32, 4), 256, 0, stream>>>(W_q, W_kv, W_p, Wq_t, Wkv_t, Wp_t);

  const float SC = 11.5415603f;  // 8 * log2(e)
  qkv_gemm<<<768, 256, 0, stream>>>(Xq_h, Wq_t, Qh, Xkv_h, Wkv_t, KVh, SC);

  attn_kernel<<<1024, 256, 0, stream>>>(Qh, KVh, Yh);

  gemm_lds<64, float><<<512, 256, 0, stream>>>(Yh, Wp_t, out, 4096, 1024, 1024, 1.0f);
}

// Round 6
// 224.659 us; speedup vs baseline: 1.3043x; 1.2338x over previous
//
#include <hip/hip_runtime.h>
#include <cstddef>

typedef _Float16 f16;
typedef _Float16 f16x8 __attribute__((ext_vector_type(8)));
typedef _Float16 f16x4 __attribute__((ext_vector_type(4)));
typedef _Float16 f16x2 __attribute__((ext_vector_type(2)));
typedef float f32x4 __attribute__((ext_vector_type(4)));
typedef float f32x16 __attribute__((ext_vector_type(16)));
typedef unsigned int u32;

__device__ inline float exp2_fast(float x) {
  float r;
  asm("v_exp_f32 %0, %1" : "=v"(r) : "v"(x));
  return r;
}

// Async global->LDS, 16B per lane. LDS dest is the wave-uniform base;
// HW writes base + lane*16.
__device__ inline void gl_lds16(const f16* g, f16* l) {
  __builtin_amdgcn_global_load_lds(
      (const __attribute__((address_space(1))) u32*)g,
      (__attribute__((address_space(3))) u32*)l, 16, 0, 0);
}

// ---------------------------------------------------------------------------
// Fused convert f32 -> f16 for both activation tensors (4M elems each).
// ---------------------------------------------------------------------------
__global__ __launch_bounds__(256) void cvt2_f32_f16(
    const float* __restrict__ a, const float* __restrict__ b,
    f16* __restrict__ oa, f16* __restrict__ ob) {
  int bid = blockIdx.x;
  const float* in;
  f16* out;
  if (bid < 4096) { in = a; out = oa; } else { in = b; out = ob; bid -= 4096; }
  int i = (bid * 256 + threadIdx.x) * 4;
  float4 v = *(const float4*)&in[i];
  f16x4 h;
  h[0] = (f16)v.x; h[1] = (f16)v.y; h[2] = (f16)v.z; h[3] = (f16)v.w;
  *(f16x4*)&out[i] = h;
}

// ---------------------------------------------------------------------------
// Fused transpose+convert of all three weight matrices: f32 [1024][N] ->
// f16 [N][1024]. z=0: W_q, z=1/2: W_kv halves, z=3: W_proj.
// ---------------------------------------------------------------------------
__global__ __launch_bounds__(256) void transpose3(
    const float* __restrict__ Wq, const float* __restrict__ Wkv,
    const float* __restrict__ Wp, f16* __restrict__ Wqt,
    f16* __restrict__ Wkvt, f16* __restrict__ Wpt) {
  __shared__ float t[32][33];
  int z = blockIdx.z;
  const float* in;
  f16* out;
  int N = 1024, extra = 0;
  if (z == 0) { in = Wq; out = Wqt; }
  else if (z == 3) { in = Wp; out = Wpt; }
  else { in = Wkv; out = Wkvt; N = 2048; extra = (z - 1) * 1024; }
  int tx = threadIdx.x % 32, ty = threadIdx.x / 32;
  int n0 = blockIdx.x * 32 + extra, k0 = blockIdx.y * 32;
#pragma unroll
  for (int i = 0; i < 32; i += 8)
    t[ty + i][tx] = in[(size_t)(k0 + ty + i) * N + n0 + tx];
  __syncthreads();
#pragma unroll
  for (int i = 0; i < 32; i += 8)
    out[(size_t)(n0 + ty + i) * 1024 + k0 + tx] = (f16)t[tx][ty + i];
}

// ---------------------------------------------------------------------------
// GEMM body (m97 pattern): C = scale*(A @ W), Bt = W^T f16 [N][K], A f16.
// BM=128 fixed, BN templated. BK=64, 256 thr = 4 waves (2x2).
// ---------------------------------------------------------------------------
template <int BN, typename CT>
__device__ __forceinline__ void gemm_body(
    const f16* __restrict__ A, const f16* __restrict__ Bt, CT* __restrict__ C,
    int bid, int M, int N, int K, float scale, f16* As, f16* Bs) {
  constexpr int NT = BN / 32;
  constexpr int BI = BN / 32;
  const int nb = N / BN;
  const int m0 = (bid / nb) * 128;
  const int n0 = (bid % nb) * BN;
  const int tid = threadIdx.x;
  const int w = tid >> 6, lane = tid & 63;
  const int l16 = lane & 15, quad = lane >> 4;
  const int wrow = (w >> 1) * 64, wcol = (w & 1) * (BN / 2);
  const int sr = tid >> 3, sc = (tid & 7) << 3;

  f32x4 acc[4][NT] = {};

  for (int k0 = 0; k0 < K; k0 += 64) {
#pragma unroll
    for (int i = 0; i < 4; i++)
      gl_lds16(&A[(size_t)(m0 + sr + i * 32) * K + k0 + sc],
               &As[i * 2048 + w * 512]);
#pragma unroll
    for (int i = 0; i < BI; i++)
      gl_lds16(&Bt[(size_t)(n0 + sr + i * 32) * K + k0 + sc],
               &Bs[i * 2048 + w * 512]);
    __syncthreads();

    f16x8 af[4][2], bf[NT][2];
#pragma unroll
    for (int mt = 0; mt < 4; mt++)
#pragma unroll
      for (int s = 0; s < 2; s++)
        af[mt][s] = *(const f16x8*)&As[(wrow + mt * 16 + l16) * 64 + s * 32 + quad * 8];
#pragma unroll
    for (int nt = 0; nt < NT; nt++)
#pragma unroll
      for (int s = 0; s < 2; s++)
        bf[nt][s] = *(const f16x8*)&Bs[(wcol + nt * 16 + l16) * 64 + s * 32 + quad * 8];

#pragma unroll
    for (int mt = 0; mt < 4; mt++)
#pragma unroll
      for (int nt = 0; nt < NT; nt++) {
        acc[mt][nt] = __builtin_amdgcn_mfma_f32_16x16x32_f16(af[mt][0], bf[nt][0], acc[mt][nt], 0, 0, 0);
        acc[mt][nt] = __builtin_amdgcn_mfma_f32_16x16x32_f16(af[mt][1], bf[nt][1], acc[mt][nt], 0, 0, 0);
      }
    __syncthreads();
  }

#pragma unroll
  for (int mt = 0; mt < 4; mt++)
#pragma unroll
    for (int nt = 0; nt < NT; nt++)
#pragma unroll
      for (int r = 0; r < 4; r++) {
        int row = m0 + wrow + mt * 16 + quad * 4 + r;
        int col = n0 + wcol + nt * 16 + l16;
        C[(size_t)row * N + col] = (CT)(acc[mt][nt][r] * scale);
      }
}

// Fused Q + KV projection GEMMs: blocks [0,256) -> Q (pre-scaled for
// log2-domain softmax), blocks [256,768) -> KV. 768 blocks = 3/CU.
__global__ __launch_bounds__(256) void qkv_gemm(
    const f16* __restrict__ Xq, const f16* __restrict__ Wqt, f16* __restrict__ Qh,
    const f16* __restrict__ Xkv, const f16* __restrict__ Wkvt, f16* __restrict__ KVh,
    float sc_q) {
  __shared__ f16 As[128 * 64];
  __shared__ f16 Bs[128 * 64];
  if (blockIdx.x < 256)
    gemm_body<128, f16>(Xq, Wqt, Qh, blockIdx.x, 4096, 1024, 1024, sc_q, As, Bs);
  else
    gemm_body<128, f16>(Xkv, Wkvt, KVh, blockIdx.x - 256, 4096, 2048, 1024, 1.0f, As, Bs);
}

template <int BN, typename CT>
__global__ __launch_bounds__(256) void gemm_lds(
    const f16* __restrict__ A, const f16* __restrict__ Bt, CT* __restrict__ C,
    int M, int N, int K, float scale) {
  __shared__ f16 As[128 * 64];
  __shared__ f16 Bs[BN * 64];
  gemm_body<BN, CT>(A, Bt, C, blockIdx.x, M, N, K, scale, As, Bs);
}

// ---------------------------------------------------------------------------
// Flash attention, round 6: 32x32x16 MFMA, transposed-S formulation.
//   S^T = K @ Q^T   (C-layout: col = lane&31 = q -> one q per lane)
//   O^T = V^T @ P^T (C-layout: col = q -> alpha/l scaling is per-lane scalar)
// Q-tile 128/block (4 waves x 32 q), KV-tile 64, 32 iters. Grid 512 linear;
// hb = bid&31 -> XCD = hb%8, so each (h,b)'s 512 KB KV set stays in one
// XCD's L2 (4 hb x 512 KB = 2 MB < 4 MB).
// Softmax: log2-domain (Qh pre-scaled by 8*log2(e)); per-iter reductions are
// in-register over 32 values + ONE shfl_xor(32) each for max and sum.
// Vt XOR-swizzled [d][kv]: elem (d,kv) at d*72 + ((((kv>>3)^(d>>3))<<3)|(kv&7)).
// Ps is per-wave [32 q][64 kv] (LD=72): b64 writes, b128 reads, no barrier.
// All LDS access patterns hand-checked to bank floor or free 2-way.
// ---------------------------------------------------------------------------
__global__ __launch_bounds__(256) void attn_kernel(
    const f16* __restrict__ Qh, const f16* __restrict__ KVh, f16* __restrict__ Yh) {
  __shared__ f16 smem[18432];          // 36.9 KB
  f16* Ks = smem;                      // [64 kv][72]
  f16* Vt = smem + 64 * 72;            // [64 d][72] swizzled
  f16* Ps = smem + 2 * 64 * 72;        // 4 x [32 q][72]

  const int bid = blockIdx.x;
  const int hb = bid & 31;
  const int qt = bid >> 5;
  const int h = hb >> 1, b = hb & 1;
  const int tid = threadIdx.x;
  const int w = tid >> 6, lane = tid & 63;
  const int l31 = lane & 31, e = lane >> 5;

  const size_t qrow0 = (size_t)b * 2048 + (size_t)qt * 128;
  const size_t kvrow0 = (size_t)b * 2048;
  f16* Psw = Ps + w * 32 * 72;

  // Q as B-operand of S^T: B[k=d][n=q], lane holds 8 d for q = l31.
  f16x8 qf[4];
#pragma unroll
  for (int ks = 0; ks < 4; ks++)
    qf[ks] = *(const f16x8*)&Qh[(qrow0 + w * 32 + l31) * 1024 + h * 64 + ks * 16 + e * 8];

  float m_run = -1e30f, l_run = 0.0f;
  f32x16 o_acc[2] = {};

  // staging maps
  const int ksr = tid >> 2, ksc = (tid & 3) << 4;   // K: row, col (2 x b128)
  const int vkv0 = (tid >> 3) * 2;                  // V: kv pair
  const int vd0 = (tid & 7) * 8;                    // V: d group
  const int vcol = ((((vkv0 >> 3) ^ (tid & 7)) << 3) | (vkv0 & 7));

  // prefetch tile 0 into registers
  f16x8 kr0, kr1, vr0, vr1;
  {
    const f16* kb = &KVh[(kvrow0 + ksr) * 2048 + h * 64 + ksc];
    kr0 = *(const f16x8*)kb;
    kr1 = *(const f16x8*)(kb + 8);
    const f16* vb = &KVh[(kvrow0 + vkv0) * 2048 + 1024 + h * 64 + vd0];
    vr0 = *(const f16x8*)vb;
    vr1 = *(const f16x8*)(vb + 2048);
  }

  for (int t = 0; t < 32; t++) {
    // ---- commit prefetched tile to LDS ----
    *(f16x8*)&Ks[ksr * 72 + ksc] = kr0;
    *(f16x8*)&Ks[ksr * 72 + ksc + 8] = kr1;
#pragma unroll
    for (int j = 0; j < 8; j++) {
      f16x2 p; p[0] = vr0[j]; p[1] = vr1[j];
      *(f16x2*)&Vt[(vd0 + j) * 72 + vcol] = p;
    }
    __syncthreads();

    // ---- issue next tile's global loads (hidden under compute) ----
    if (t + 1 < 32) {
      const f16* kb = &KVh[(kvrow0 + (t + 1) * 64 + ksr) * 2048 + h * 64 + ksc];
      kr0 = *(const f16x8*)kb;
      kr1 = *(const f16x8*)(kb + 8);
      const f16* vb = &KVh[(kvrow0 + (t + 1) * 64 + vkv0) * 2048 + 1024 + h * 64 + vd0];
      vr0 = *(const f16x8*)vb;
      vr1 = *(const f16x8*)(vb + 2048);
    }

    // ---- S^T = K @ Q^T : per lane 32 scores, all for q = l31 ----
    // kv(reg, kvt) = kvt*32 + (reg&3) + 4*e + 8*(reg>>2)
    f32x16 sacc[2] = {};
#pragma unroll
    for (int kvt = 0; kvt < 2; kvt++)
#pragma unroll
      for (int ks = 0; ks < 4; ks++) {
        f16x8 a = *(const f16x8*)&Ks[(kvt * 32 + l31) * 72 + ks * 16 + e * 8];
        sacc[kvt] = __builtin_amdgcn_mfma_f32_32x32x16_f16(a, qf[ks], sacc[kvt], 0, 0, 0);
      }

    // ---- online softmax (log2 domain), per-lane scalar state ----
    float mx = sacc[0][0];
#pragma unroll
    for (int r = 1; r < 16; r++) mx = fmaxf(mx, sacc[0][r]);
#pragma unroll
    for (int r = 0; r < 16; r++) mx = fmaxf(mx, sacc[1][r]);
    mx = fmaxf(mx, __shfl_xor(mx, 32, 64));
    float mnew = fmaxf(m_run, mx);
    float alpha = exp2_fast(m_run - mnew);
    m_run = mnew;

    float ssum = 0.0f;
#pragma unroll
    for (int kvt = 0; kvt < 2; kvt++)
#pragma unroll
      for (int r = 0; r < 16; r++) {
        float p = exp2_fast(sacc[kvt][r] - mnew);
        sacc[kvt][r] = p;
        ssum += p;
      }
    ssum += __shfl_xor(ssum, 32, 64);
    l_run = l_run * alpha + ssum;
#pragma unroll
    for (int r = 0; r < 16; r++) { o_acc[0][r] *= alpha; o_acc[1][r] *= alpha; }

    // ---- P -> per-wave LDS [q][kv], b64 writes (4 consecutive kv) ----
#pragma unroll
    for (int kvt = 0; kvt < 2; kvt++)
#pragma unroll
      for (int r2 = 0; r2 < 4; r2++) {
        f16x4 hh;
        hh[0] = (f16)sacc[kvt][r2 * 4 + 0];
        hh[1] = (f16)sacc[kvt][r2 * 4 + 1];
        hh[2] = (f16)sacc[kvt][r2 * 4 + 2];
        hh[3] = (f16)sacc[kvt][r2 * 4 + 3];
        *(f16x4*)&Psw[l31 * 72 + kvt * 32 + r2 * 8 + e * 4] = hh;
      }
    // no barrier: Psw is private to this wave; lgkmcnt orders write->read.

    // ---- O^T += V^T @ P^T ----
    f16x8 pf[4];
#pragma unroll
    for (int ks = 0; ks < 4; ks++)
      pf[ks] = *(const f16x8*)&Psw[l31 * 72 + ks * 16 + e * 8];
#pragma unroll
    for (int dt = 0; dt < 2; dt++) {
      const int d = dt * 32 + l31;
      const int dx = d >> 3;
#pragma unroll
      for (int ks = 0; ks < 4; ks++) {
        f16x8 va = *(const f16x8*)&Vt[d * 72 + (((ks * 2 + e) ^ dx) << 3)];
        o_acc[dt] = __builtin_amdgcn_mfma_f32_32x32x16_f16(va, pf[ks], o_acc[dt], 0, 0, 0);
      }
    }
    __syncthreads();  // protect Ks/Vt before next commit
  }

  // ---- epilogue: O^T/l -> per-wave LDS [q][d] f32 -> coalesced Yh ----
  // (after the final barrier all waves are done with Ks/Vt/Ps; reuse smem)
  float linv = 1.0f / l_run;
  float* Of = (float*)smem + w * 2176;  // [32 q][68]
#pragma unroll
  for (int dt = 0; dt < 2; dt++)
#pragma unroll
    for (int r2 = 0; r2 < 4; r2++) {
      f32x4 vv;
      vv[0] = o_acc[dt][r2 * 4 + 0] * linv;
      vv[1] = o_acc[dt][r2 * 4 + 1] * linv;
      vv[2] = o_acc[dt][r2 * 4 + 2] * linv;
      vv[3] = o_acc[dt][r2 * 4 + 3] * linv;
      *(f32x4*)&Of[l31 * 68 + dt * 32 + r2 * 8 + e * 4] = vv;
    }
  // intra-wave LDS RAW ordered by lgkmcnt; Of region is wave-private.
  const int qq = lane >> 1, dh = (lane & 1) * 32;
#pragma unroll
  for (int j = 0; j < 8; j++) {
    f32x4 v = *(const f32x4*)&Of[qq * 68 + dh + j * 4];
    f16x4 hh;
    hh[0] = (f16)v[0]; hh[1] = (f16)v[1]; hh[2] = (f16)v[2]; hh[3] = (f16)v[3];
    *(f16x4*)&Yh[(qrow0 + w * 32 + qq) * 1024 + h * 64 + dh + j * 4] = hh;
  }
}

// ---------------------------------------------------------------------------
extern "C" void kernel_launch(void* const* d_in, const int* in_sizes, int n_in,
                              void* d_out, int out_size, void* d_ws, size_t ws_size,
                              hipStream_t stream) {
  const float* x_q  = (const float*)d_in[0];
  const float* x_kv = (const float*)d_in[1];
  const float* W_q  = (const float*)d_in[2];
  const float* W_kv = (const float*)d_in[3];
  const float* W_p  = (const float*)d_in[4];
  float* out = (float*)d_out;

  f16* Wq_t  = (f16*)d_ws;                       // [1024][1024]
  f16* Wkv_t = Wq_t  + (size_t)1024 * 1024;      // [2048][1024]
  f16* Wp_t  = Wkv_t + (size_t)2048 * 1024;      // [1024][1024]
  f16* Qh    = Wp_t  + (size_t)1024 * 1024;      // [4096][1024]
  f16* KVh   = Qh    + (size_t)4096 * 1024;      // [4096][2048]
  f16* Yh    = KVh   + (size_t)4096 * 2048;      // [4096][1024]
  f16* Xq_h  = Yh;                               // alias (dead after qkv_gemm)
  f16* Xkv_h = Yh    + (size_t)4096 * 1024;      // [4096][1024]

  cvt2_f32_f16<<<8192, 256, 0, stream>>>(x_q, x_kv, Xq_h, Xkv_h);
  transpose3<<<dim3(32, 32, 4), 256, 0, stream>>>(W_q, W_kv, W_p, Wq_t, Wkv_t, Wp_t);

  const float SC = 11.5415603f;  // 8 * log2(e)
  qkv_gemm<<<768, 256, 0, stream>>>(Xq_h, Wq_t, Qh, Xkv_h, Wkv_t, KVh, SC);

  attn_kernel<<<512, 256, 0, stream>>>(Qh, KVh, Yh);

  gemm_lds<64, float><<<512, 256, 0, stream>>>(Yh, Wp_t, out, 4096, 1024, 1024, 1.0f);
}

// Round 7
// 212.039 us; speedup vs baseline: 1.3819x; 1.0595x over previous
//
#include <hip/hip_runtime.h>
#include <cstddef>

typedef _Float16 f16;
typedef _Float16 f16x8 __attribute__((ext_vector_type(8)));
typedef _Float16 f16x4 __attribute__((ext_vector_type(4)));
typedef _Float16 f16x2 __attribute__((ext_vector_type(2)));
typedef float f32x4 __attribute__((ext_vector_type(4)));
typedef float f32x16 __attribute__((ext_vector_type(16)));
typedef unsigned int u32;

__device__ inline float exp2_fast(float x) {
  float r;
  asm("v_exp_f32 %0, %1" : "=v"(r) : "v"(x));
  return r;
}

// ---------------------------------------------------------------------------
// Fused prep: blocks [0,8192) stream-convert x_q/x_kv f32->f16;
// blocks [8192,12288) transpose+convert the three weight matrices.
// ---------------------------------------------------------------------------
__global__ __launch_bounds__(256) void prep(
    const float* __restrict__ xq, const float* __restrict__ xkv,
    f16* __restrict__ oq, f16* __restrict__ okv,
    const float* __restrict__ Wq, const float* __restrict__ Wkv,
    const float* __restrict__ Wp, f16* __restrict__ Wqt,
    f16* __restrict__ Wkvt, f16* __restrict__ Wpt) {
  __shared__ float t[32][33];
  int bid = blockIdx.x;
  if (bid < 8192) {
    const float* in = (bid < 4096) ? xq : xkv;
    f16* out = (bid < 4096) ? oq : okv;
    int i = ((bid & 4095) * 256 + threadIdx.x) * 4;
    float4 v = *(const float4*)&in[i];
    f16x4 h;
    h[0] = (f16)v.x; h[1] = (f16)v.y; h[2] = (f16)v.z; h[3] = (f16)v.w;
    *(f16x4*)&out[i] = h;
  } else {
    int zz = bid - 8192;
    int bx = zz & 31, by = (zz >> 5) & 31, z = zz >> 10;
    const float* in;
    f16* out;
    int N = 1024, extra = 0;
    if (z == 0) { in = Wq; out = Wqt; }
    else if (z == 3) { in = Wp; out = Wpt; }
    else { in = Wkv; out = Wkvt; N = 2048; extra = (z - 1) * 1024; }
    int tx = threadIdx.x % 32, ty = threadIdx.x / 32;
    int n0 = bx * 32 + extra, k0 = by * 32;
#pragma unroll
    for (int i = 0; i < 32; i += 8)
      t[ty + i][tx] = in[(size_t)(k0 + ty + i) * N + n0 + tx];
    __syncthreads();
#pragma unroll
    for (int i = 0; i < 32; i += 8)
      out[(size_t)(n0 + ty + i) * 1024 + k0 + tx] = (f16)t[tx][ty + i];
  }
}

// ---------------------------------------------------------------------------
// GEMM body, round 7: register-prefetch pipeline + XOR-swizzled LDS.
// C = scale*(A @ W), Bt = W^T f16 [N][K], A f16. BM=128, BN templated,
// BK=64, 256 thr = 4 waves (2x2), wave tile 64 x BN/2, 16x16x32 MFMA.
// LDS layout: elem (row, col) at row*64 + ((col8 ^ (row&7))<<3 | col&7) —
// staging writes AND frag reads both hit the 8-phase bank floor (vs 2x floor
// for the linear layout, where row stride 128B makes all rows bank-alias).
// Tile t+1's global loads are issued right after the barrier, draining at
// the END-of-iter barrier -> one compute phase of latency hiding.
// ---------------------------------------------------------------------------
template <int BN, typename CT>
__device__ __forceinline__ void gemm_body(
    const f16* __restrict__ A, const f16* __restrict__ Bt, CT* __restrict__ C,
    int bid, int M, int N, int K, float scale, f16* As, f16* Bs) {
  constexpr int NT = BN / 32;
  constexpr int BI = BN / 32;
  const int nb = N / BN;
  const int m0 = (bid / nb) * 128;
  const int n0 = (bid % nb) * BN;
  const int tid = threadIdx.x;
  const int w = tid >> 6, lane = tid & 63;
  const int l16 = lane & 15, quad = lane >> 4;
  const int wrow = (w >> 1) * 64, wcol = (w & 1) * (BN / 2);
  const int sr = tid >> 3, sc8 = tid & 7;
  const int wc8 = sc8 ^ (sr & 7);  // swizzled write col-group

  f32x4 acc[4][NT] = {};
  f16x8 ar[4], br[BI];

#pragma unroll
  for (int i = 0; i < 4; i++)
    ar[i] = *(const f16x8*)&A[(size_t)(m0 + sr + i * 32) * K + sc8 * 8];
#pragma unroll
  for (int i = 0; i < BI; i++)
    br[i] = *(const f16x8*)&Bt[(size_t)(n0 + sr + i * 32) * K + sc8 * 8];

  for (int k0 = 0; k0 < K; k0 += 64) {
    // ---- commit prefetched tile (swizzled, bank-floor b128 writes) ----
#pragma unroll
    for (int i = 0; i < 4; i++)
      *(f16x8*)&As[(sr + i * 32) * 64 + wc8 * 8] = ar[i];
#pragma unroll
    for (int i = 0; i < BI; i++)
      *(f16x8*)&Bs[(sr + i * 32) * 64 + wc8 * 8] = br[i];
    __syncthreads();

    // ---- issue next tile's loads (hidden under this tile's compute) ----
    if (k0 + 64 < K) {
#pragma unroll
      for (int i = 0; i < 4; i++)
        ar[i] = *(const f16x8*)&A[(size_t)(m0 + sr + i * 32) * K + k0 + 64 + sc8 * 8];
#pragma unroll
      for (int i = 0; i < BI; i++)
        br[i] = *(const f16x8*)&Bt[(size_t)(n0 + sr + i * 32) * K + k0 + 64 + sc8 * 8];
    }

    // ---- fragments (swizzled reads, bank floor) + MFMA ----
    f16x8 bf[NT][2];
#pragma unroll
    for (int nt = 0; nt < NT; nt++) {
      const int row = wcol + nt * 16 + l16;
#pragma unroll
      for (int s = 0; s < 2; s++)
        bf[nt][s] = *(const f16x8*)&Bs[row * 64 + (((s * 4 + quad) ^ (row & 7)) << 3)];
    }
#pragma unroll
    for (int mt = 0; mt < 4; mt++) {
      const int row = wrow + mt * 16 + l16;
      f16x8 af0 = *(const f16x8*)&As[row * 64 + ((quad ^ (row & 7)) << 3)];
      f16x8 af1 = *(const f16x8*)&As[row * 64 + (((4 + quad) ^ (row & 7)) << 3)];
#pragma unroll
      for (int nt = 0; nt < NT; nt++) {
        acc[mt][nt] = __builtin_amdgcn_mfma_f32_16x16x32_f16(af0, bf[nt][0], acc[mt][nt], 0, 0, 0);
        acc[mt][nt] = __builtin_amdgcn_mfma_f32_16x16x32_f16(af1, bf[nt][1], acc[mt][nt], 0, 0, 0);
      }
    }
    __syncthreads();
  }

#pragma unroll
  for (int mt = 0; mt < 4; mt++)
#pragma unroll
    for (int nt = 0; nt < NT; nt++)
#pragma unroll
      for (int r = 0; r < 4; r++) {
        int row = m0 + wrow + mt * 16 + quad * 4 + r;
        int col = n0 + wcol + nt * 16 + l16;
        C[(size_t)row * N + col] = (CT)(acc[mt][nt][r] * scale);
      }
}

// Fused Q + KV projection GEMMs: blocks [0,256) -> Q (pre-scaled for
// log2-domain softmax), blocks [256,768) -> KV. 768 blocks = 3/CU;
// launch_bounds(256,3) caps VGPR ~170 so all 3 stay co-resident.
__global__ __launch_bounds__(256, 3) void qkv_gemm(
    const f16* __restrict__ Xq, const f16* __restrict__ Wqt, f16* __restrict__ Qh,
    const f16* __restrict__ Xkv, const f16* __restrict__ Wkvt, f16* __restrict__ KVh,
    float sc_q) {
  __shared__ f16 As[128 * 64];
  __shared__ f16 Bs[128 * 64];
  if (blockIdx.x < 256)
    gemm_body<128, f16>(Xq, Wqt, Qh, blockIdx.x, 4096, 1024, 1024, sc_q, As, Bs);
  else
    gemm_body<128, f16>(Xkv, Wkvt, KVh, blockIdx.x - 256, 4096, 2048, 1024, 1.0f, As, Bs);
}

template <int BN, typename CT>
__global__ __launch_bounds__(256, 2) void gemm_lds(
    const f16* __restrict__ A, const f16* __restrict__ Bt, CT* __restrict__ C,
    int M, int N, int K, float scale) {
  __shared__ f16 As[128 * 64];
  __shared__ f16 Bs[BN * 64];
  gemm_body<BN, CT>(A, Bt, C, blockIdx.x, M, N, K, scale, As, Bs);
}

// ---------------------------------------------------------------------------
// Flash attention (unchanged from round 6 — control). 32x32x16 MFMA,
// transposed-S formulation; Qh pre-scaled by 8*log2(e); XCD-aware swizzle.
// ---------------------------------------------------------------------------
__global__ __launch_bounds__(256) void attn_kernel(
    const f16* __restrict__ Qh, const f16* __restrict__ KVh, f16* __restrict__ Yh) {
  __shared__ f16 smem[18432];
  f16* Ks = smem;                      // [64 kv][72]
  f16* Vt = smem + 64 * 72;            // [64 d][72] swizzled
  f16* Ps = smem + 2 * 64 * 72;        // 4 x [32 q][72]

  const int bid = blockIdx.x;
  const int hb = bid & 31;
  const int qt = bid >> 5;
  const int h = hb >> 1, b = hb & 1;
  const int tid = threadIdx.x;
  const int w = tid >> 6, lane = tid & 63;
  const int l31 = lane & 31, e = lane >> 5;

  const size_t qrow0 = (size_t)b * 2048 + (size_t)qt * 128;
  const size_t kvrow0 = (size_t)b * 2048;
  f16* Psw = Ps + w * 32 * 72;

  f16x8 qf[4];
#pragma unroll
  for (int ks = 0; ks < 4; ks++)
    qf[ks] = *(const f16x8*)&Qh[(qrow0 + w * 32 + l31) * 1024 + h * 64 + ks * 16 + e * 8];

  float m_run = -1e30f, l_run = 0.0f;
  f32x16 o_acc[2] = {};

  const int ksr = tid >> 2, ksc = (tid & 3) << 4;
  const int vkv0 = (tid >> 3) * 2;
  const int vd0 = (tid & 7) * 8;
  const int vcol = ((((vkv0 >> 3) ^ (tid & 7)) << 3) | (vkv0 & 7));

  f16x8 kr0, kr1, vr0, vr1;
  {
    const f16* kb = &KVh[(kvrow0 + ksr) * 2048 + h * 64 + ksc];
    kr0 = *(const f16x8*)kb;
    kr1 = *(const f16x8*)(kb + 8);
    const f16* vb = &KVh[(kvrow0 + vkv0) * 2048 + 1024 + h * 64 + vd0];
    vr0 = *(const f16x8*)vb;
    vr1 = *(const f16x8*)(vb + 2048);
  }

  for (int t = 0; t < 32; t++) {
    *(f16x8*)&Ks[ksr * 72 + ksc] = kr0;
    *(f16x8*)&Ks[ksr * 72 + ksc + 8] = kr1;
#pragma unroll
    for (int j = 0; j < 8; j++) {
      f16x2 p; p[0] = vr0[j]; p[1] = vr1[j];
      *(f16x2*)&Vt[(vd0 + j) * 72 + vcol] = p;
    }
    __syncthreads();

    if (t + 1 < 32) {
      const f16* kb = &KVh[(kvrow0 + (t + 1) * 64 + ksr) * 2048 + h * 64 + ksc];
      kr0 = *(const f16x8*)kb;
      kr1 = *(const f16x8*)(kb + 8);
      const f16* vb = &KVh[(kvrow0 + (t + 1) * 64 + vkv0) * 2048 + 1024 + h * 64 + vd0];
      vr0 = *(const f16x8*)vb;
      vr1 = *(const f16x8*)(vb + 2048);
    }

    f32x16 sacc[2] = {};
#pragma unroll
    for (int kvt = 0; kvt < 2; kvt++)
#pragma unroll
      for (int ks = 0; ks < 4; ks++) {
        f16x8 a = *(const f16x8*)&Ks[(kvt * 32 + l31) * 72 + ks * 16 + e * 8];
        sacc[kvt] = __builtin_amdgcn_mfma_f32_32x32x16_f16(a, qf[ks], sacc[kvt], 0, 0, 0);
      }

    float mx = sacc[0][0];
#pragma unroll
    for (int r = 1; r < 16; r++) mx = fmaxf(mx, sacc[0][r]);
#pragma unroll
    for (int r = 0; r < 16; r++) mx = fmaxf(mx, sacc[1][r]);
    mx = fmaxf(mx, __shfl_xor(mx, 32, 64));
    float mnew = fmaxf(m_run, mx);
    float alpha = exp2_fast(m_run - mnew);
    m_run = mnew;

    float ssum = 0.0f;
#pragma unroll
    for (int kvt = 0; kvt < 2; kvt++)
#pragma unroll
      for (int r = 0; r < 16; r++) {
        float p = exp2_fast(sacc[kvt][r] - mnew);
        sacc[kvt][r] = p;
        ssum += p;
      }
    ssum += __shfl_xor(ssum, 32, 64);
    l_run = l_run * alpha + ssum;
#pragma unroll
    for (int r = 0; r < 16; r++) { o_acc[0][r] *= alpha; o_acc[1][r] *= alpha; }

#pragma unroll
    for (int kvt = 0; kvt < 2; kvt++)
#pragma unroll
      for (int r2 = 0; r2 < 4; r2++) {
        f16x4 hh;
        hh[0] = (f16)sacc[kvt][r2 * 4 + 0];
        hh[1] = (f16)sacc[kvt][r2 * 4 + 1];
        hh[2] = (f16)sacc[kvt][r2 * 4 + 2];
        hh[3] = (f16)sacc[kvt][r2 * 4 + 3];
        *(f16x4*)&Psw[l31 * 72 + kvt * 32 + r2 * 8 + e * 4] = hh;
      }

    f16x8 pf[4];
#pragma unroll
    for (int ks = 0; ks < 4; ks++)
      pf[ks] = *(const f16x8*)&Psw[l31 * 72 + ks * 16 + e * 8];
#pragma unroll
    for (int dt = 0; dt < 2; dt++) {
      const int d = dt * 32 + l31;
      const int dx = d >> 3;
#pragma unroll
      for (int ks = 0; ks < 4; ks++) {
        f16x8 va = *(const f16x8*)&Vt[d * 72 + (((ks * 2 + e) ^ dx) << 3)];
        o_acc[dt] = __builtin_amdgcn_mfma_f32_32x32x16_f16(va, pf[ks], o_acc[dt], 0, 0, 0);
      }
    }
    __syncthreads();
  }

  float linv = 1.0f / l_run;
  float* Of = (float*)smem + w * 2176;  // [32 q][68]
#pragma unroll
  for (int dt = 0; dt < 2; dt++)
#pragma unroll
    for (int r2 = 0; r2 < 4; r2++) {
      f32x4 vv;
      vv[0] = o_acc[dt][r2 * 4 + 0] * linv;
      vv[1] = o_acc[dt][r2 * 4 + 1] * linv;
      vv[2] = o_acc[dt][r2 * 4 + 2] * linv;
      vv[3] = o_acc[dt][r2 * 4 + 3] * linv;
      *(f32x4*)&Of[l31 * 68 + dt * 32 + r2 * 8 + e * 4] = vv;
    }
  const int qq = lane >> 1, dh = (lane & 1) * 32;
#pragma unroll
  for (int j = 0; j < 8; j++) {
    f32x4 v = *(const f32x4*)&Of[qq * 68 + dh + j * 4];
    f16x4 hh;
    hh[0] = (f16)v[0]; hh[1] = (f16)v[1]; hh[2] = (f16)v[2]; hh[3] = (f16)v[3];
    *(f16x4*)&Yh[(qrow0 + w * 32 + qq) * 1024 + h * 64 + dh + j * 4] = hh;
  }
}

// ---------------------------------------------------------------------------
extern "C" void kernel_launch(void* const* d_in, const int* in_sizes, int n_in,
                              void* d_out, int out_size, void* d_ws, size_t ws_size,
                              hipStream_t stream) {
  const float* x_q  = (const float*)d_in[0];
  const float* x_kv = (const float*)d_in[1];
  const float* W_q  = (const float*)d_in[2];
  const float* W_kv = (const float*)d_in[3];
  const float* W_p  = (const float*)d_in[4];
  float* out = (float*)d_out;

  f16* Wq_t  = (f16*)d_ws;                       // [1024][1024]
  f16* Wkv_t = Wq_t  + (size_t)1024 * 1024;      // [2048][1024]
  f16* Wp_t  = Wkv_t + (size_t)2048 * 1024;      // [1024][1024]
  f16* Qh    = Wp_t  + (size_t)1024 * 1024;      // [4096][1024]
  f16* KVh   = Qh    + (size_t)4096 * 1024;      // [4096][2048]
  f16* Yh    = KVh   + (size_t)4096 * 2048;      // [4096][1024]
  f16* Xq_h  = Yh;                               // alias (dead after qkv_gemm)
  f16* Xkv_h = Yh    + (size_t)4096 * 1024;      // [4096][1024]

  prep<<<12288, 256, 0, stream>>>(x_q, x_kv, Xq_h, Xkv_h,
                                  W_q, W_kv, W_p, Wq_t, Wkv_t, Wp_t);

  const float SC = 11.5415603f;  // 8 * log2(e)
  qkv_gemm<<<768, 256, 0, stream>>>(Xq_h, Wq_t, Qh, Xkv_h, Wkv_t, KVh, SC);

  attn_kernel<<<512, 256, 0, stream>>>(Qh, KVh, Yh);

  gemm_lds<64, float><<<512, 256, 0, stream>>>(Yh, Wp_t, out, 4096, 1024, 1024, 1.0f);
}